// Round 8
// baseline (172.756 us; speedup 1.0000x reference)
//
#include <hip/hip_runtime.h>
#include <hip/hip_bf16.h>
#include <hip/hip_fp16.h>
#include <math.h>

// AutoCorrelation (Autoformer). B=16, L=2048, H=8, E=64, fp32.
// Round 8: fp16 LDS spectra. Identical structure/barriers to validated r7
// (512 threads, 4 channels, 4 single-purpose regions, float4 loads, XCD
// swizzle), but inter-stage spectra are stored as __half2 (4B/complex):
// LDS 69.6KB -> 34.8KB -> 4 blocks/CU (32 waves, was 16). All arithmetic
// fp32 in registers; only LDS storage is rounded. Final acc staging stays
// fp32 (re/im planes, |P| can exceed fp16 range). Twiddles scoped per stage
// to hold VGPR <= 64 (launch_bounds(512,8)).
// reduce/ifft/topk/aggregate byte-identical to validated r4/r7.

#define B_ 16
#define L_ 2048
#define H_ 8
#define E_ 64
#define C_ (H_ * E_)      // 512 channels per batch
#define NCH (B_ * C_)     // 8192
#define NBLK (NCH / 4)    // 2048 fft blocks
#define K_ 7
#define PAD_ 2176         // 2048 + 2048/16 words per region

// ---------- workspace layout ----------
#define PART_OFF 0ull                              // float2[2048][2048] = 32 MiB
#define SG_OFF   33554432ull                       // float2[16][8][2048] = 2 MiB
#define MV_OFF   (SG_OFF + 2097152ull)             // float [B][L]
#define TK_OFF   (MV_OFF + 131072ull)              // int[7]
#define W_OFF    (TK_OFF + 64ull)                  // float[16][7]

// ---------- complex helpers ----------
__device__ __forceinline__ float2 cadd(float2 a, float2 b) { return make_float2(a.x + b.x, a.y + b.y); }
__device__ __forceinline__ float2 csub(float2 a, float2 b) { return make_float2(a.x - b.x, a.y - b.y); }
__device__ __forceinline__ float2 cmul(float2 a, float2 b) {
  return make_float2(fmaf(a.x, b.x, -a.y * b.y), fmaf(a.x, b.y, a.y * b.x));
}
__device__ __forceinline__ float2 cis(float ang) { float s, c; sincosf(ang, &s, &c); return make_float2(c, s); }

template<int S> __device__ __forceinline__ float2 rot90(float2 z) {  // *W_4^{S}: S=-1 -> -i*z
  return (S < 0) ? make_float2(z.y, -z.x) : make_float2(-z.y, z.x);
}
template<int S> __device__ __forceinline__ void dft4(float2& a, float2& b, float2& c, float2& d) {
  float2 t0 = cadd(a, c), t1 = csub(a, c), t2 = cadd(b, d), t3 = rot90<S>(csub(b, d));
  a = cadd(t0, t2); c = csub(t0, t2); b = cadd(t1, t3); d = csub(t1, t3);
}
template<int S> __device__ __forceinline__ void dft8(float2 v[8]) {
  const float RT = 0.70710678118654752f;
  const float SR = (S < 0) ? -RT : RT;
  float2 a0 = cadd(v[0], v[4]), a1 = cadd(v[1], v[5]), a2 = cadd(v[2], v[6]), a3 = cadd(v[3], v[7]);
  float2 b0 = csub(v[0], v[4]), b1 = csub(v[1], v[5]), b2 = csub(v[2], v[6]), b3 = csub(v[3], v[7]);
  b1 = cmul(b1, make_float2(RT, SR));     // W8^{S}
  b2 = rot90<S>(b2);                      // W8^{2S}
  b3 = cmul(b3, make_float2(-RT, SR));    // W8^{3S}
  dft4<S>(a0, a1, a2, a3);
  dft4<S>(b0, b1, b2, b3);
  v[0] = a0; v[2] = a1; v[4] = a2; v[6] = a3;
  v[1] = b0; v[3] = b1; v[5] = b2; v[7] = b3;
}
// padded LDS word index: +1 word per 16 (<=2-way across all stage patterns)
__device__ __forceinline__ int sg(int e) { return e + (e >> 4); }

__device__ __forceinline__ float2 ld16(const __half2* p) { return __half22float2(*p); }
__device__ __forceinline__ void st16(__half2* p, float2 v) { *p = __float22half2_rn(v); }

// ---------- kernel F: fused load + radix-8/8/8/4 DIF FFT + freq product ----------
// 512 threads, 4 channels/block, 4 single-purpose fp16 LDS regions.
// Digit-reversed storage p = 256k1+32k2+4k3+k4, frequency f = k1+8k2+64k3+512k4.
__global__ __launch_bounds__(512, 8) void fft_corr_kernel(
    const float* __restrict__ q, const float* __restrict__ k,
    float2* __restrict__ part) {
  extern __shared__ __half2 dbuf[];       // 4 regions x PAD_ half2 = 34816 B
  int tid = threadIdx.x;
  int t = tid & 255;                      // local lane within half
  int half = tid >> 8;                    // 0: ch0,1 (regions 0,1); 1: ch2,3 (2,3)
  int j2 = t & 31, j3 = t & 3;
  // XCD swizzle (r4-proven): the 4 logical blocks sharing each 64B q/k line
  // map to the same physical p&7 (same XCD) and are dispatched 8 apart.
  int pphys = blockIdx.x;
  int i = pphys >> 3, x = pphys & 7;
  int l = ((i >> 2) << 5) | (x << 2) | (i & 3);     // bijective on [0,2048)
  int cbase = l * 4;
  int b = cbase >> 9, h = (cbase >> 6) & 7, e0 = cbase & 63;
  size_t base = (size_t)b * (L_ * H_ * E_) + (size_t)h * E_ + e0;

  // ---- phase L: 512 threads x 4 taps, float4 q + float4 k each; stage raw
  // z = (q_c, k_c) into region c (fp16). Same 4096 float4 loads/block as r7.
  {
    float4 qv[4], kv[4];
#pragma unroll
    for (int j = 0; j < 4; ++j) {
      int tau = t + 256 * (4 * half + j);
      size_t a = base + (size_t)tau * (H_ * E_);
      qv[j] = *(const float4*)(q + a);
      kv[j] = *(const float4*)(k + a);
    }
#pragma unroll
    for (int j = 0; j < 4; ++j) {
      int sp = sg(t + 256 * (4 * half + j));
      st16(&dbuf[0 * PAD_ + sp], make_float2(qv[j].x, kv[j].x));
      st16(&dbuf[1 * PAD_ + sp], make_float2(qv[j].y, kv[j].y));
      st16(&dbuf[2 * PAD_ + sp], make_float2(qv[j].z, kv[j].z));
      st16(&dbuf[3 * PAD_ + sp], make_float2(qv[j].w, kv[j].w));
    }
  }
  __syncthreads();                        // raw taps visible to both halves

  __half2* A  = dbuf + (2 * half) * PAD_;
  __half2* Bf = dbuf + (2 * half + 1) * PAD_;

  // ---- stage 1 (M=2048), in-place per region (read set == write set)
  {
    float2 tw1[7];
    {
      float2 w1 = cis(-6.283185307179586f * (float)t / 2048.0f);
      tw1[0] = w1;
#pragma unroll
      for (int kk = 1; kk < 7; ++kk) tw1[kk] = cmul(tw1[kk - 1], w1);
    }
    float2 v[8];
#pragma unroll
    for (int m = 0; m < 8; ++m) v[m] = ld16(&A[sg(t + 256 * m)]);
    dft8<-1>(v);
#pragma unroll
    for (int kk = 1; kk < 8; ++kk) v[kk] = cmul(v[kk], tw1[kk - 1]);
#pragma unroll
    for (int kk = 0; kk < 8; ++kk) st16(&A[sg(t + 256 * kk)], v[kk]);
#pragma unroll
    for (int m = 0; m < 8; ++m) v[m] = ld16(&Bf[sg(t + 256 * m)]);
    dft8<-1>(v);
#pragma unroll
    for (int kk = 1; kk < 8; ++kk) v[kk] = cmul(v[kk], tw1[kk - 1]);
#pragma unroll
    for (int kk = 0; kk < 8; ++kk) st16(&Bf[sg(t + 256 * kk)], v[kk]);
  }
  __syncthreads();

  int base2 = (t >> 5) * 256 + j2;
  int base3 = (t >> 2) * 32 + j3;
  float2 va[8], vb[8];
  // ---- stage 2 (M=256); per-thread read set == write set
  {
    float2 tw2[7];
    {
      float2 w2 = cis(-6.283185307179586f * (float)j2 / 256.0f);
      tw2[0] = w2;
#pragma unroll
      for (int kk = 1; kk < 7; ++kk) tw2[kk] = cmul(tw2[kk - 1], w2);
    }
#pragma unroll
    for (int m = 0; m < 8; ++m) { va[m] = ld16(&A[sg(base2 + 32 * m)]); vb[m] = ld16(&Bf[sg(base2 + 32 * m)]); }
    dft8<-1>(va); dft8<-1>(vb);
#pragma unroll
    for (int kk = 1; kk < 8; ++kk) { va[kk] = cmul(va[kk], tw2[kk - 1]); vb[kk] = cmul(vb[kk], tw2[kk - 1]); }
#pragma unroll
    for (int kk = 0; kk < 8; ++kk) { st16(&A[sg(base2 + 32 * kk)], va[kk]); st16(&Bf[sg(base2 + 32 * kk)], vb[kk]); }
  }
  __syncthreads();
  // ---- stage 3 (M=32)
  {
    float2 tw3[7];
    {
      float2 w3 = cis(-6.283185307179586f * (float)j3 / 32.0f);
      tw3[0] = w3;
#pragma unroll
      for (int kk = 1; kk < 7; ++kk) tw3[kk] = cmul(tw3[kk - 1], w3);
    }
#pragma unroll
    for (int m = 0; m < 8; ++m) { va[m] = ld16(&A[sg(base3 + 4 * m)]); vb[m] = ld16(&Bf[sg(base3 + 4 * m)]); }
    dft8<-1>(va); dft8<-1>(vb);
#pragma unroll
    for (int kk = 1; kk < 8; ++kk) { va[kk] = cmul(va[kk], tw3[kk - 1]); vb[kk] = cmul(vb[kk], tw3[kk - 1]); }
#pragma unroll
    for (int kk = 0; kk < 8; ++kk) { st16(&A[sg(base3 + 4 * kk)], va[kk]); st16(&Bf[sg(base3 + 4 * kk)], vb[kk]); }
  }
  __syncthreads();
  // ---- stage 4 (M=4 radix-4, thread-private quads)
#pragma unroll
  for (int kk = 0; kk < 8; ++kk) { va[kk] = ld16(&A[sg(8 * t + kk)]); vb[kk] = ld16(&Bf[sg(8 * t + kk)]); }
  dft4<-1>(va[0], va[1], va[2], va[3]); dft4<-1>(va[4], va[5], va[6], va[7]);
  dft4<-1>(vb[0], vb[1], vb[2], vb[3]); dft4<-1>(vb[4], vb[5], vb[6], vb[7]);
#pragma unroll
  for (int kk = 0; kk < 8; ++kk) { st16(&A[sg(8 * t + kk)], va[kk]); st16(&Bf[sg(8 * t + kk)], vb[kk]); }
  __syncthreads();
  // ---- product: P = Qf*conj(Kf) via two-real trick; -f by digit arithmetic.
  // va/vb are the unrounded fp32 stage-4 values; Bc comes from fp16 LDS.
  float2 acc[8];
#pragma unroll
  for (int kk = 0; kk < 8; ++kk) {
    int pos = 8 * t + kk;
    int f  = ((pos >> 8) & 7) | (((pos >> 5) & 7) << 3) | (((pos >> 2) & 7) << 6) | ((pos & 3) << 9);
    int fp = (2048 - f) & 2047;
    int pp = ((fp & 7) << 8) | (((fp >> 3) & 7) << 5) | (((fp >> 6) & 7) << 2) | ((fp >> 9) & 3);
    float2 Ax = va[kk], Bc = ld16(&A[sg(pp)]);
    acc[kk].x = 0.5f  * (Bc.x * Ax.y + Bc.y * Ax.x);
    acc[kk].y = 0.25f * (Ax.x * Ax.x + Ax.y * Ax.y - Bc.x * Bc.x - Bc.y * Bc.y);
    Ax = vb[kk]; Bc = ld16(&Bf[sg(pp)]);
    acc[kk].x += 0.5f  * (Bc.x * Ax.y + Bc.y * Ax.x);
    acc[kk].y += 0.25f * (Ax.x * Ax.x + Ax.y * Ax.y - Bc.x * Bc.x - Bc.y * Bc.y);
  }
  __syncthreads();                        // all product reads of A/Bf done
  // half h parks its pair-sum FP32 in planes 2h (re) and 2h+1 (im)
  {
    float* fre = (float*)(dbuf + (2 * half) * PAD_);
    float* fim = (float*)(dbuf + (2 * half + 1) * PAD_);
#pragma unroll
    for (int kk = 0; kk < 8; ++kk) {
      int sp = sg(8 * t + kk);
      fre[sp] = acc[kk].x;
      fim[sp] = acc[kk].y;
    }
  }
  __syncthreads();
  // final cross-half sum + coalesced 512-wide store (row = LOGICAL block id)
  {
    const float* r0 = (const float*)dbuf;
    const float* i0 = (const float*)(dbuf + PAD_);
    const float* r1 = (const float*)(dbuf + 2 * PAD_);
    const float* i1 = (const float*)(dbuf + 3 * PAD_);
    float2* prow = part + (size_t)l * L_;
#pragma unroll
    for (int m = 0; m < 4; ++m) {
      int p = tid + 512 * m;
      int sp = sg(p);
      prow[p] = make_float2(r0[sp] + r1[sp], i0[sp] + i1[sp]);
    }
  }
}

// ---------- kernel R: sum 16 partial rows -> Sg[b][g][p] ----------
__global__ __launch_bounds__(256) void reduce_R_kernel(
    const float2* __restrict__ part, float2* __restrict__ Sg) {
  int idx = blockIdx.x * 256 + threadIdx.x;   // 0..262143 = [b][g][p]
  int p = idx & 2047;
  int g = (idx >> 11) & 7;
  int b = idx >> 14;
  float2 s = make_float2(0.f, 0.f);
#pragma unroll 4
  for (int i = 0; i < 16; ++i) {
    float2 vv = part[(size_t)(b * 128 + g * 16 + i) * L_ + p];
    s.x += vv.x; s.y += vv.y;
  }
  Sg[idx] = s;
}

// ---------- kernel I: sum 8 group-partials + mirrored DIT inverse ----------
__global__ __launch_bounds__(256) void ifft_kernel(
    const float2* __restrict__ Sg, float* __restrict__ mv) {
  __shared__ float2 buf[PAD_];
  int t = threadIdx.x, b = blockIdx.x;
  int j2 = t & 31, j3 = t & 3;
  float2 tw1[7], tw2[7], tw3[7];
  {
    float2 w1 = cis(6.283185307179586f * (float)t  / 2048.0f);
    float2 w2 = cis(6.283185307179586f * (float)j2 / 256.0f);
    float2 w3 = cis(6.283185307179586f * (float)j3 / 32.0f);
    tw1[0] = w1; tw2[0] = w2; tw3[0] = w3;
#pragma unroll
    for (int kk = 1; kk < 7; ++kk) {
      tw1[kk] = cmul(tw1[kk - 1], w1);
      tw2[kk] = cmul(tw2[kk - 1], w2);
      tw3[kk] = cmul(tw3[kk - 1], w3);
    }
  }
  int base2 = (t >> 5) * 256 + j2;
  int base3 = (t >> 2) * 32 + j3;
  // stage A: final 8-way reduction + M=4 DFT (no twiddle), quads 8t..8t+7
  float2 u[8];
#pragma unroll
  for (int kk = 0; kk < 8; ++kk) u[kk] = make_float2(0.f, 0.f);
#pragma unroll
  for (int g = 0; g < 8; ++g) {
    const float4* rp = (const float4*)(Sg + (size_t)(b * 8 + g) * L_);
#pragma unroll
    for (int m = 0; m < 4; ++m) {
      float4 f = rp[4 * t + m];
      u[2 * m].x     += f.x; u[2 * m].y     += f.y;
      u[2 * m + 1].x += f.z; u[2 * m + 1].y += f.w;
    }
  }
  dft4<1>(u[0], u[1], u[2], u[3]);
  dft4<1>(u[4], u[5], u[6], u[7]);
#pragma unroll
  for (int kk = 0; kk < 8; ++kk) buf[sg(8 * t + kk)] = u[kk];
  __syncthreads();
  // stage B: M=32 (twiddle inputs, then inverse DFT)
  float2 v[8];
#pragma unroll
  for (int kk = 0; kk < 8; ++kk) v[kk] = buf[sg(base3 + 4 * kk)];
#pragma unroll
  for (int kk = 1; kk < 8; ++kk) v[kk] = cmul(v[kk], tw3[kk - 1]);
  dft8<1>(v);
  __syncthreads();
#pragma unroll
  for (int m = 0; m < 8; ++m) buf[sg(base3 + 4 * m)] = v[m];
  __syncthreads();
  // stage C: M=256
#pragma unroll
  for (int kk = 0; kk < 8; ++kk) v[kk] = buf[sg(base2 + 32 * kk)];
#pragma unroll
  for (int kk = 1; kk < 8; ++kk) v[kk] = cmul(v[kk], tw2[kk - 1]);
  dft8<1>(v);
  __syncthreads();
#pragma unroll
  for (int m = 0; m < 8; ++m) buf[sg(base2 + 32 * m)] = v[m];
  __syncthreads();
  // stage D: M=2048 -> natural-order x[t+256m]
#pragma unroll
  for (int kk = 0; kk < 8; ++kk) v[kk] = buf[sg(t + 256 * kk)];
#pragma unroll
  for (int kk = 1; kk < 8; ++kk) v[kk] = cmul(v[kk], tw1[kk - 1]);
  dft8<1>(v);
  const float scale = 1.0f / (2048.0f * 512.0f);  // 1/N * mean over H*E
#pragma unroll
  for (int m = 0; m < 8; ++m) mv[b * L_ + t + 256 * m] = v[m].x * scale;
}

// ---------- kernel K: batch-mean top-7 + per-batch softmax weights ----------
__global__ __launch_bounds__(256) void topk_kernel(
    const float* __restrict__ mv, int* __restrict__ topk, float* __restrict__ wts) {
  __shared__ float av[2048];
  __shared__ float rv[256];
  __shared__ int   ri[256];
  __shared__ int   sidx[K_];
  int tid = threadIdx.x;
  for (int d = tid; d < 2048; d += 256) {
    float s = 0.f;
#pragma unroll
    for (int b = 0; b < B_; ++b) s += mv[b * L_ + d];
    av[d] = s;
  }
  __syncthreads();
  for (int kk = 0; kk < K_; ++kk) {
    float bv = -INFINITY; int bi = 0;
    for (int d = tid; d < 2048; d += 256) {
      float vv = av[d];
      if (vv > bv) { bv = vv; bi = d; }
    }
    rv[tid] = bv; ri[tid] = bi;
    __syncthreads();
    for (int off = 128; off > 0; off >>= 1) {
      if (tid < off) {
        float v2 = rv[tid + off]; int i2 = ri[tid + off];
        if (v2 > rv[tid] || (v2 == rv[tid] && i2 < ri[tid])) { rv[tid] = v2; ri[tid] = i2; }
      }
      __syncthreads();
    }
    if (tid == 0) { sidx[kk] = ri[0]; av[ri[0]] = -INFINITY; }
    __syncthreads();
  }
  if (tid < K_) topk[tid] = sidx[tid];
  if (tid < B_) {
    float xk[K_], m = -INFINITY;
#pragma unroll
    for (int kk = 0; kk < K_; ++kk) { xk[kk] = mv[tid * L_ + sidx[kk]]; m = fmaxf(m, xk[kk]); }
    float s = 0.f;
#pragma unroll
    for (int kk = 0; kk < K_; ++kk) { xk[kk] = expf(xk[kk] - m); s += xk[kk]; }
#pragma unroll
    for (int kk = 0; kk < K_; ++kk) wts[tid * K_ + kk] = xk[kk] / s;
  }
}

// ---------- kernel G: out[b,t,h,e] = sum_k w[b,k] * v[b,(t+d_k)%L,h,e] ----------
__global__ __launch_bounds__(256) void aggregate_kernel(
    const float4* __restrict__ v4, const int* __restrict__ topk,
    const float* __restrict__ wts, float4* __restrict__ out4) {
  __shared__ int   sidx[K_];
  __shared__ float sw[B_][K_];
  int tid = threadIdx.x;
  if (tid < K_) sidx[tid] = topk[tid];
  if (tid < B_ * K_) sw[tid / K_][tid % K_] = wts[tid];
  __syncthreads();
  int idx = blockIdx.x * 256 + tid;
  int c4  = idx & 127;
  int row = idx >> 7;
  int t   = row & (L_ - 1);
  int b   = row >> 11;
  float4 acc = make_float4(0.f, 0.f, 0.f, 0.f);
#pragma unroll
  for (int kk = 0; kk < K_; ++kk) {
    int s = t + sidx[kk];
    if (s >= L_) s -= L_;
    float w = sw[b][kk];
    float4 val = v4[((size_t)(b * L_ + s) << 7) + c4];
    acc.x += w * val.x; acc.y += w * val.y;
    acc.z += w * val.z; acc.w += w * val.w;
  }
  out4[idx] = acc;
}

extern "C" void kernel_launch(void* const* d_in, const int* in_sizes, int n_in,
                              void* d_out, int out_size, void* d_ws, size_t ws_size,
                              hipStream_t stream) {
  const float* q = (const float*)d_in[0];
  const float* k = (const float*)d_in[1];
  const float* v = (const float*)d_in[2];
  float* out = (float*)d_out;

  char* ws = (char*)d_ws;
  float2* part = (float2*)(ws + PART_OFF);
  float2* Sg   = (float2*)(ws + SG_OFF);
  float*  mv   = (float*) (ws + MV_OFF);
  int*    topk = (int*)   (ws + TK_OFF);
  float*  wts  = (float*) (ws + W_OFF);

  fft_corr_kernel<<<NBLK, 512, 4 * PAD_ * sizeof(__half2), stream>>>(q, k, part);
  reduce_R_kernel<<<(B_ * 8 * L_) / 256, 256, 0, stream>>>(part, Sg);
  ifft_kernel<<<B_, 256, 0, stream>>>(Sg, mv);
  topk_kernel<<<1, 256, 0, stream>>>(mv, topk, wts);
  aggregate_kernel<<<(B_ * L_ * C_ / 4) / 256, 256, 0, stream>>>(
      (const float4*)v, topk, wts, (float4*)out);
}

// Round 9
// 159.630 us; speedup vs baseline: 1.0822x; 1.0822x over previous
//
#include <hip/hip_runtime.h>
#include <hip/hip_bf16.h>
#include <hip/hip_fp16.h>
#include <math.h>

// AutoCorrelation (Autoformer). B=16, L=2048, H=8, E=64, fp32.
// Round 9: fully-coalesced loads. One block = 16 e-channels = exactly one
// 64B line per (b,tau,h); every line fetched once, 100% consumed (r4-r8's
// scattered pattern touched 4x the lines at 25% utilization and was
// occupancy-invariant ~112us). 16 fp16 LDS regions (stride 2178 words =
// 2 mod 32: staging scatter 2-way/free), 512 threads, 4 passes x 4 channels
// with the r7/r8-validated single-purpose-region barrier structure.
// part shrinks to 512 rows (8 MiB); reduce_R folded into ifft (32-row sum).
// All FFT arithmetic fp32 in registers; LDS spectra fp16 (r8-proven).

#define B_ 16
#define L_ 2048
#define H_ 8
#define E_ 64
#define NBLK 512          // 16b x 8h x 4 e-groups of 16 channels
#define K_ 7
#define RS_ 2178          // region stride in 4B words (2178 % 32 == 2)

// ---------- workspace layout ----------
#define PART_OFF 0ull                              // float2[512][2048] = 8 MiB
#define MV_OFF   8388608ull                        // float [B][L]
#define TK_OFF   (MV_OFF + 131072ull)              // int[7]
#define W_OFF    (TK_OFF + 64ull)                  // float[16][7]

// ---------- complex helpers ----------
__device__ __forceinline__ float2 cadd(float2 a, float2 b) { return make_float2(a.x + b.x, a.y + b.y); }
__device__ __forceinline__ float2 csub(float2 a, float2 b) { return make_float2(a.x - b.x, a.y - b.y); }
__device__ __forceinline__ float2 cmul(float2 a, float2 b) {
  return make_float2(fmaf(a.x, b.x, -a.y * b.y), fmaf(a.x, b.y, a.y * b.x));
}
__device__ __forceinline__ float2 cis(float ang) { float s, c; sincosf(ang, &s, &c); return make_float2(c, s); }

template<int S> __device__ __forceinline__ float2 rot90(float2 z) {  // *W_4^{S}: S=-1 -> -i*z
  return (S < 0) ? make_float2(z.y, -z.x) : make_float2(-z.y, z.x);
}
template<int S> __device__ __forceinline__ void dft4(float2& a, float2& b, float2& c, float2& d) {
  float2 t0 = cadd(a, c), t1 = csub(a, c), t2 = cadd(b, d), t3 = rot90<S>(csub(b, d));
  a = cadd(t0, t2); c = csub(t0, t2); b = cadd(t1, t3); d = csub(t1, t3);
}
template<int S> __device__ __forceinline__ void dft8(float2 v[8]) {
  const float RT = 0.70710678118654752f;
  const float SR = (S < 0) ? -RT : RT;
  float2 a0 = cadd(v[0], v[4]), a1 = cadd(v[1], v[5]), a2 = cadd(v[2], v[6]), a3 = cadd(v[3], v[7]);
  float2 b0 = csub(v[0], v[4]), b1 = csub(v[1], v[5]), b2 = csub(v[2], v[6]), b3 = csub(v[3], v[7]);
  b1 = cmul(b1, make_float2(RT, SR));     // W8^{S}
  b2 = rot90<S>(b2);                      // W8^{2S}
  b3 = cmul(b3, make_float2(-RT, SR));    // W8^{3S}
  dft4<S>(a0, a1, a2, a3);
  dft4<S>(b0, b1, b2, b3);
  v[0] = a0; v[2] = a1; v[4] = a2; v[6] = a3;
  v[1] = b0; v[3] = b1; v[5] = b2; v[7] = b3;
}
// padded in-region index: +1 word per 16 (<=2-way across all stage patterns)
__device__ __forceinline__ int sg(int e) { return e + (e >> 4); }

__device__ __forceinline__ float2 ld16(const __half2* p) { return __half22float2(*p); }
__device__ __forceinline__ void st16(__half2* p, float2 v) { *p = __float22half2_rn(v); }

// ---------- kernel F: coalesced load + radix-8/8/8/4 DIF FFT + freq product ----------
// Block: 16 channels (one 64B line wide), 512 threads, 16 fp16 LDS regions.
// 4 passes; pass p: half h handles channels 4p+2h, 4p+2h+1 (regions = channel).
// Digit-reversed storage pos = 256k1+32k2+4k3+k4, frequency f = k1+8k2+64k3+512k4.
__global__ __launch_bounds__(512) void fft_corr_kernel(
    const float* __restrict__ q, const float* __restrict__ k,
    float2* __restrict__ part) {
  extern __shared__ __half2 dbuf[];       // 16 regions x RS_ words = 139392 B
  int tid = threadIdx.x;
  int t = tid & 255;                      // lane within half
  int half = tid >> 8;
  int j2 = t & 31, j3 = t & 3;
  int l = blockIdx.x;                     // 0..511
  int eg = l & 3, h = (l >> 2) & 7, b = l >> 5;
  size_t base = (size_t)b * (L_ * H_ * E_) + (size_t)h * E_ + eg * 16;

  // ---- staging: fully-coalesced float4 reads; each wave-load = 16 whole lines.
  // lane = (tau0, f4): f4 walks the 4 float4s of the 64B line.
  {
    int f4 = tid & 3, tau0 = tid >> 2;
#pragma unroll 4
    for (int m = 0; m < 16; ++m) {
      int tau = tau0 + 128 * m;
      size_t a = base + (size_t)tau * (H_ * E_) + f4 * 4;
      float4 q4 = *(const float4*)(q + a);
      float4 k4 = *(const float4*)(k + a);
      int sp = sg(tau);
      st16(&dbuf[(4 * f4 + 0) * RS_ + sp], make_float2(q4.x, k4.x));
      st16(&dbuf[(4 * f4 + 1) * RS_ + sp], make_float2(q4.y, k4.y));
      st16(&dbuf[(4 * f4 + 2) * RS_ + sp], make_float2(q4.z, k4.z));
      st16(&dbuf[(4 * f4 + 3) * RS_ + sp], make_float2(q4.w, k4.w));
    }
  }
  __syncthreads();                        // all 16 regions staged

  // twiddles (t-dependent, shared by all passes)
  float2 tw1[7], tw2[7], tw3[7];
  {
    float2 w1 = cis(-6.283185307179586f * (float)t  / 2048.0f);
    float2 w2 = cis(-6.283185307179586f * (float)j2 / 256.0f);
    float2 w3 = cis(-6.283185307179586f * (float)j3 / 32.0f);
    tw1[0] = w1; tw2[0] = w2; tw3[0] = w3;
#pragma unroll
    for (int kk = 1; kk < 7; ++kk) {
      tw1[kk] = cmul(tw1[kk - 1], w1);
      tw2[kk] = cmul(tw2[kk - 1], w2);
      tw3[kk] = cmul(tw3[kk - 1], w3);
    }
  }
  int base2 = (t >> 5) * 256 + j2;
  int base3 = (t >> 2) * 32 + j3;
  float2 acc[8];
#pragma unroll
  for (int kk = 0; kk < 8; ++kk) acc[kk] = make_float2(0.f, 0.f);

  for (int p = 0; p < 4; ++p) {
    __half2* A  = dbuf + (size_t)(4 * p + 2 * half) * RS_;
    __half2* Bf = A + RS_;
    float2 va[8], vb[8];
    // ---- stage 1 (M=2048), in-place (read set == write set per thread)
#pragma unroll
    for (int m = 0; m < 8; ++m) { va[m] = ld16(&A[sg(t + 256 * m)]); vb[m] = ld16(&Bf[sg(t + 256 * m)]); }
    dft8<-1>(va); dft8<-1>(vb);
#pragma unroll
    for (int kk = 1; kk < 8; ++kk) { va[kk] = cmul(va[kk], tw1[kk - 1]); vb[kk] = cmul(vb[kk], tw1[kk - 1]); }
#pragma unroll
    for (int kk = 0; kk < 8; ++kk) { st16(&A[sg(t + 256 * kk)], va[kk]); st16(&Bf[sg(t + 256 * kk)], vb[kk]); }
    __syncthreads();
    // ---- stage 2 (M=256)
#pragma unroll
    for (int m = 0; m < 8; ++m) { va[m] = ld16(&A[sg(base2 + 32 * m)]); vb[m] = ld16(&Bf[sg(base2 + 32 * m)]); }
    dft8<-1>(va); dft8<-1>(vb);
#pragma unroll
    for (int kk = 1; kk < 8; ++kk) { va[kk] = cmul(va[kk], tw2[kk - 1]); vb[kk] = cmul(vb[kk], tw2[kk - 1]); }
#pragma unroll
    for (int kk = 0; kk < 8; ++kk) { st16(&A[sg(base2 + 32 * kk)], va[kk]); st16(&Bf[sg(base2 + 32 * kk)], vb[kk]); }
    __syncthreads();
    // ---- stage 3 (M=32)
#pragma unroll
    for (int m = 0; m < 8; ++m) { va[m] = ld16(&A[sg(base3 + 4 * m)]); vb[m] = ld16(&Bf[sg(base3 + 4 * m)]); }
    dft8<-1>(va); dft8<-1>(vb);
#pragma unroll
    for (int kk = 1; kk < 8; ++kk) { va[kk] = cmul(va[kk], tw3[kk - 1]); vb[kk] = cmul(vb[kk], tw3[kk - 1]); }
#pragma unroll
    for (int kk = 0; kk < 8; ++kk) { st16(&A[sg(base3 + 4 * kk)], va[kk]); st16(&Bf[sg(base3 + 4 * kk)], vb[kk]); }
    __syncthreads();
    // ---- stage 4 (M=4 radix-4, thread-private quads)
#pragma unroll
    for (int kk = 0; kk < 8; ++kk) { va[kk] = ld16(&A[sg(8 * t + kk)]); vb[kk] = ld16(&Bf[sg(8 * t + kk)]); }
    dft4<-1>(va[0], va[1], va[2], va[3]); dft4<-1>(va[4], va[5], va[6], va[7]);
    dft4<-1>(vb[0], vb[1], vb[2], vb[3]); dft4<-1>(vb[4], vb[5], vb[6], vb[7]);
#pragma unroll
    for (int kk = 0; kk < 8; ++kk) { st16(&A[sg(8 * t + kk)], va[kk]); st16(&Bf[sg(8 * t + kk)], vb[kk]); }
    __syncthreads();
    // ---- product: P = Qf*conj(Kf), -f by digit arithmetic; accumulate.
    // (next pass touches DIFFERENT regions -> no trailing barrier needed)
#pragma unroll
    for (int kk = 0; kk < 8; ++kk) {
      int pos = 8 * t + kk;
      int f  = ((pos >> 8) & 7) | (((pos >> 5) & 7) << 3) | (((pos >> 2) & 7) << 6) | ((pos & 3) << 9);
      int fp = (2048 - f) & 2047;
      int pp = ((fp & 7) << 8) | (((fp >> 3) & 7) << 5) | (((fp >> 6) & 7) << 2) | ((fp >> 9) & 3);
      float2 Ax = va[kk], Bc = ld16(&A[sg(pp)]);
      acc[kk].x += 0.5f  * (Bc.x * Ax.y + Bc.y * Ax.x);
      acc[kk].y += 0.25f * (Ax.x * Ax.x + Ax.y * Ax.y - Bc.x * Bc.x - Bc.y * Bc.y);
      Ax = vb[kk]; Bc = ld16(&Bf[sg(pp)]);
      acc[kk].x += 0.5f  * (Bc.x * Ax.y + Bc.y * Ax.x);
      acc[kk].y += 0.25f * (Ax.x * Ax.x + Ax.y * Ax.y - Bc.x * Bc.x - Bc.y * Bc.y);
    }
  }
  // park per-half sums FP32: half 0 -> planes 0(re),1(im); half 1 -> 2,3.
  // Regions 0-3 are dead (pass-0 product reads completed before pass-1's
  // first barrier). |P| summed over 8 channels can exceed fp16 range -> fp32.
  {
    float* fre = (float*)dbuf + (size_t)(2 * half) * RS_;
    float* fim = fre + RS_;
#pragma unroll
    for (int kk = 0; kk < 8; ++kk) {
      int sp = sg(8 * t + kk);
      fre[sp] = acc[kk].x;
      fim[sp] = acc[kk].y;
    }
  }
  __syncthreads();
  // cross-half sum + coalesced 512-wide store
  {
    const float* r0 = (const float*)dbuf;
    const float* i0 = r0 + RS_;
    const float* r1 = r0 + 2 * RS_;
    const float* i1 = r0 + 3 * RS_;
    float2* prow = part + (size_t)l * L_;
#pragma unroll
    for (int m = 0; m < 4; ++m) {
      int p = tid + 512 * m;
      int sp = sg(p);
      prow[p] = make_float2(r0[sp] + r1[sp], i0[sp] + i1[sp]);
    }
  }
}

// ---------- kernel I: sum 32 partial rows + mirrored DIT inverse ----------
__global__ __launch_bounds__(256) void ifft_kernel(
    const float2* __restrict__ part, float* __restrict__ mv) {
  __shared__ float2 buf[2176];
  int t = threadIdx.x, b = blockIdx.x;
  int j2 = t & 31, j3 = t & 3;
  float2 tw1[7], tw2[7], tw3[7];
  {
    float2 w1 = cis(6.283185307179586f * (float)t  / 2048.0f);
    float2 w2 = cis(6.283185307179586f * (float)j2 / 256.0f);
    float2 w3 = cis(6.283185307179586f * (float)j3 / 32.0f);
    tw1[0] = w1; tw2[0] = w2; tw3[0] = w3;
#pragma unroll
    for (int kk = 1; kk < 7; ++kk) {
      tw1[kk] = cmul(tw1[kk - 1], w1);
      tw2[kk] = cmul(tw2[kk - 1], w2);
      tw3[kk] = cmul(tw3[kk - 1], w3);
    }
  }
  int base2 = (t >> 5) * 256 + j2;
  int base3 = (t >> 2) * 32 + j3;
  // stage A: 32-row reduction + M=4 DFT (no twiddle), quads 8t..8t+7
  float2 u[8];
#pragma unroll
  for (int kk = 0; kk < 8; ++kk) u[kk] = make_float2(0.f, 0.f);
#pragma unroll 4
  for (int g = 0; g < 32; ++g) {
    const float4* rp = (const float4*)(part + (size_t)(b * 32 + g) * L_);
#pragma unroll
    for (int m = 0; m < 4; ++m) {
      float4 f = rp[4 * t + m];
      u[2 * m].x     += f.x; u[2 * m].y     += f.y;
      u[2 * m + 1].x += f.z; u[2 * m + 1].y += f.w;
    }
  }
  dft4<1>(u[0], u[1], u[2], u[3]);
  dft4<1>(u[4], u[5], u[6], u[7]);
#pragma unroll
  for (int kk = 0; kk < 8; ++kk) buf[sg(8 * t + kk)] = u[kk];
  __syncthreads();
  // stage B: M=32 (twiddle inputs, then inverse DFT)
  float2 v[8];
#pragma unroll
  for (int kk = 0; kk < 8; ++kk) v[kk] = buf[sg(base3 + 4 * kk)];
#pragma unroll
  for (int kk = 1; kk < 8; ++kk) v[kk] = cmul(v[kk], tw3[kk - 1]);
  dft8<1>(v);
  __syncthreads();
#pragma unroll
  for (int m = 0; m < 8; ++m) buf[sg(base3 + 4 * m)] = v[m];
  __syncthreads();
  // stage C: M=256
#pragma unroll
  for (int kk = 0; kk < 8; ++kk) v[kk] = buf[sg(base2 + 32 * kk)];
#pragma unroll
  for (int kk = 1; kk < 8; ++kk) v[kk] = cmul(v[kk], tw2[kk - 1]);
  dft8<1>(v);
  __syncthreads();
#pragma unroll
  for (int m = 0; m < 8; ++m) buf[sg(base2 + 32 * m)] = v[m];
  __syncthreads();
  // stage D: M=2048 -> natural-order x[t+256m]
#pragma unroll
  for (int kk = 0; kk < 8; ++kk) v[kk] = buf[sg(t + 256 * kk)];
#pragma unroll
  for (int kk = 1; kk < 8; ++kk) v[kk] = cmul(v[kk], tw1[kk - 1]);
  dft8<1>(v);
  const float scale = 1.0f / (2048.0f * 512.0f);  // 1/N * mean over H*E
#pragma unroll
  for (int m = 0; m < 8; ++m) mv[b * L_ + t + 256 * m] = v[m].x * scale;
}

// ---------- kernel K: batch-mean top-7 + per-batch softmax weights ----------
__global__ __launch_bounds__(256) void topk_kernel(
    const float* __restrict__ mv, int* __restrict__ topk, float* __restrict__ wts) {
  __shared__ float av[2048];
  __shared__ float rv[256];
  __shared__ int   ri[256];
  __shared__ int   sidx[K_];
  int tid = threadIdx.x;
  for (int d = tid; d < 2048; d += 256) {
    float s = 0.f;
#pragma unroll
    for (int b = 0; b < B_; ++b) s += mv[b * L_ + d];
    av[d] = s;
  }
  __syncthreads();
  for (int kk = 0; kk < K_; ++kk) {
    float bv = -INFINITY; int bi = 0;
    for (int d = tid; d < 2048; d += 256) {
      float vv = av[d];
      if (vv > bv) { bv = vv; bi = d; }
    }
    rv[tid] = bv; ri[tid] = bi;
    __syncthreads();
    for (int off = 128; off > 0; off >>= 1) {
      if (tid < off) {
        float v2 = rv[tid + off]; int i2 = ri[tid + off];
        if (v2 > rv[tid] || (v2 == rv[tid] && i2 < ri[tid])) { rv[tid] = v2; ri[tid] = i2; }
      }
      __syncthreads();
    }
    if (tid == 0) { sidx[kk] = ri[0]; av[ri[0]] = -INFINITY; }
    __syncthreads();
  }
  if (tid < K_) topk[tid] = sidx[tid];
  if (tid < B_) {
    float xk[K_], m = -INFINITY;
#pragma unroll
    for (int kk = 0; kk < K_; ++kk) { xk[kk] = mv[tid * L_ + sidx[kk]]; m = fmaxf(m, xk[kk]); }
    float s = 0.f;
#pragma unroll
    for (int kk = 0; kk < K_; ++kk) { xk[kk] = expf(xk[kk] - m); s += xk[kk]; }
#pragma unroll
    for (int kk = 0; kk < K_; ++kk) wts[tid * K_ + kk] = xk[kk] / s;
  }
}

// ---------- kernel G: out[b,t,h,e] = sum_k w[b,k] * v[b,(t+d_k)%L,h,e] ----------
__global__ __launch_bounds__(256) void aggregate_kernel(
    const float4* __restrict__ v4, const int* __restrict__ topk,
    const float* __restrict__ wts, float4* __restrict__ out4) {
  __shared__ int   sidx[K_];
  __shared__ float sw[B_][K_];
  int tid = threadIdx.x;
  if (tid < K_) sidx[tid] = topk[tid];
  if (tid < B_ * K_) sw[tid / K_][tid % K_] = wts[tid];
  __syncthreads();
  int idx = blockIdx.x * 256 + tid;
  int c4  = idx & 127;
  int row = idx >> 7;
  int t   = row & (L_ - 1);
  int b   = row >> 11;
  float4 acc = make_float4(0.f, 0.f, 0.f, 0.f);
#pragma unroll
  for (int kk = 0; kk < K_; ++kk) {
    int s = t + sidx[kk];
    if (s >= L_) s -= L_;
    float w = sw[b][kk];
    float4 val = v4[((size_t)(b * L_ + s) << 7) + c4];
    acc.x += w * val.x; acc.y += w * val.y;
    acc.z += w * val.z; acc.w += w * val.w;
  }
  out4[idx] = acc;
}

extern "C" void kernel_launch(void* const* d_in, const int* in_sizes, int n_in,
                              void* d_out, int out_size, void* d_ws, size_t ws_size,
                              hipStream_t stream) {
  const float* q = (const float*)d_in[0];
  const float* k = (const float*)d_in[1];
  const float* v = (const float*)d_in[2];
  float* out = (float*)d_out;

  char* ws = (char*)d_ws;
  float2* part = (float2*)(ws + PART_OFF);
  float*  mv   = (float*) (ws + MV_OFF);
  int*    topk = (int*)   (ws + TK_OFF);
  float*  wts  = (float*) (ws + W_OFF);

  fft_corr_kernel<<<NBLK, 512, 16 * RS_ * 4, stream>>>(q, k, part);
  ifft_kernel<<<B_, 256, 0, stream>>>(part, mv);
  topk_kernel<<<1, 256, 0, stream>>>(mv, topk, wts);
  aggregate_kernel<<<(B_ * L_ * H_ * E_ / 4) / 256, 256, 0, stream>>>(
      (const float4*)v, topk, wts, (float4*)out);
}